// Round 10
// baseline (3510.308 us; speedup 1.0000x reference)
//
#include <hip/hip_runtime.h>
#include <hip/hip_bf16.h>

// EdgeSHLayer probe R10: 4-variant A/B, each REPEAT=6 so each dispatch gets its
// own rocprof top-5 row (fills are ~310 us; 6 iters puts every variant above).
//   M3: skeleton  — no gather/compute, LDS drain, regular stores (store ceiling)
//   M2: direct    — full math, scalar strided stores, no LDS/barrier
//   M1: LDS+reg   — full math, LDS drain, regular stores
//   M0: LDS+nt    — current kernel (control anchor, must run LAST -> correct out)
// Output identical to single-pass reference (M0 last writer).

#define TILE 256
#define REPEAT 6

typedef float nfloat4 __attribute__((ext_vector_type(4)));

__global__ __launch_bounds__(256) void pack_pos_kernel(
    const float* __restrict__ pos, float4* __restrict__ pos4, int N)
{
    int i = blockIdx.x * 256 + threadIdx.x;
    if (i < N) {
        pos4[i] = make_float4(pos[3 * i + 0], pos[3 * i + 1], pos[3 * i + 2], 0.0f);
    }
}

template <int MODE>
__global__ __launch_bounds__(TILE) void edge_sh_kernel(
    const int*    __restrict__ edge,   // [2, E]
    const float4* __restrict__ pos4,   // [N]
    const float*  __restrict__ radius, // [1]
    float*        __restrict__ out,    // [E*10 + E*9]
    int E)
{
    constexpr bool USE_GATHER = (MODE != 3);
    constexpr bool USE_LDS    = (MODE != 2);
    constexpr bool USE_NT     = (MODE == 0);

    __shared__ __align__(16) float lds[TILE * 10 + TILE * 9];
    float* lds_emb = lds;
    float* lds_sh  = lds + TILE * 10;

    const int tid = threadIdx.x;
    const long long base_e = (long long)blockIdx.x * TILE;
    const long long e = base_e + tid;
    const bool valid = (e < (long long)E);

    const float end = radius[0];
    const float inv_step = 11.0f / end;

    const long long rem_edges = (long long)E - base_e;
    const int n_emb4 = (int)((rem_edges >= TILE ? (long long)TILE * 10
                                                : rem_edges * 10) / 4);
    const int n_sh4  = (int)((rem_edges >= TILE ? (long long)TILE * 9
                                                : rem_edges * 9 ) / 4);

    #pragma unroll 1
    for (int rep = 0; rep < REPEAT; ++rep) {
        float emb[10];
        float sh[9];

        if (USE_GATHER) {
            float vx = 0.0f, vy = 0.0f, vz = 0.0f;
            if (valid) {
                int s = __builtin_nontemporal_load(&edge[e]);
                int d = __builtin_nontemporal_load(&edge[(long long)E + e]);
                float4 a = pos4[s];
                float4 b = pos4[d];
                vx = b.x - a.x; vy = b.y - a.y; vz = b.z - a.z;
            }
            float len2 = vx * vx + vy * vy + vz * vz;
            float len  = sqrtf(len2);

            const float ls = len * inv_step;
            #pragma unroll
            for (int j = 0; j < 10; ++j) {
                float d = ls - (float)(j + 1);
                float t = __builtin_fmaf(-d, d, 1.0f);
                float val = (t > 0.0f)
                          ? 26.669299714f * __expf(__fdividef(-2.0f, t))
                          : 0.0f;
                if (!valid) val = 0.0f;
                emb[j] = val;
            }

            float inv = 1.0f / fmaxf(len, 1e-12f);
            float x = vx * inv, y = vy * inv, z = vz * inv;
            const float S3 = 1.7320508075688772f;
            sh[0] = valid ? 1.0f : 0.0f;
            sh[1] = x;  sh[2] = y;  sh[3] = z;
            sh[4] = S3 * x * z;
            sh[5] = S3 * x * y;
            sh[6] = y * y - 0.5f * (x * x + z * z);
            sh[7] = S3 * y * z;
            sh[8] = 0.5f * S3 * (z * z - x * x);
        } else {
            // skeleton: deterministic cheap values, same store structure
            #pragma unroll
            for (int j = 0; j < 10; ++j) emb[j] = (float)(j + (tid & 7));
            #pragma unroll
            for (int k = 0; k < 9;  ++k) sh[k]  = (float)(k ^ (tid & 3));
        }

        if (USE_LDS) {
            #pragma unroll
            for (int j = 0; j < 10; ++j) lds_emb[tid * 10 + j] = emb[j];
            #pragma unroll
            for (int k = 0; k < 9;  ++k) lds_sh[tid * 9 + k]  = sh[k];

            __syncthreads();

            nfloat4* g_emb = (nfloat4*)(out + base_e * 10);
            const nfloat4* l_emb = (const nfloat4*)lds_emb;
            #pragma unroll
            for (int i = 0; i < 3; ++i) {
                int idx = tid + i * TILE;
                if (idx < n_emb4) {
                    if (USE_NT) __builtin_nontemporal_store(l_emb[idx], &g_emb[idx]);
                    else        g_emb[idx] = l_emb[idx];
                }
            }

            nfloat4* g_sh = (nfloat4*)(out + (long long)E * 10 + base_e * 9);
            const nfloat4* l_sh = (const nfloat4*)lds_sh;
            #pragma unroll
            for (int i = 0; i < 3; ++i) {
                int idx = tid + i * TILE;
                if (idx < n_sh4) {
                    if (USE_NT) __builtin_nontemporal_store(l_sh[idx], &g_sh[idx]);
                    else        g_sh[idx] = l_sh[idx];
                }
            }
            __syncthreads();   // LDS reuse across reps
        } else {
            // direct scalar strided stores (L2 write-combining test)
            if (valid) {
                float* pe = out + e * 10;
                #pragma unroll
                for (int j = 0; j < 10; ++j) pe[j] = emb[j];
                float* ps = out + (long long)E * 10 + e * 9;
                #pragma unroll
                for (int k = 0; k < 9; ++k) ps[k] = sh[k];
            }
        }
    }
}

extern "C" void kernel_launch(void* const* d_in, const int* in_sizes, int n_in,
                              void* d_out, int out_size, void* d_ws, size_t ws_size,
                              hipStream_t stream) {
    const float* pos    = (const float*)d_in[1];
    const float* radius = (const float*)d_in[2];
    const int*   edge   = (const int*)d_in[3];
    float*       out    = (float*)d_out;

    const int N = in_sizes[1] / 3;
    const int E = in_sizes[3] / 2;

    float4* pos4 = (float4*)d_ws;

    hipLaunchKernelGGL(pack_pos_kernel, dim3((N + 255) / 256), dim3(256), 0, stream,
                       pos, pos4, N);

    const int nblk = (E + TILE - 1) / TILE;
    // Order matters: last writer (M0) leaves the verified-correct output.
    hipLaunchKernelGGL(edge_sh_kernel<3>, dim3(nblk), dim3(TILE), 0, stream,
                       edge, pos4, radius, out, E);   // skeleton
    hipLaunchKernelGGL(edge_sh_kernel<2>, dim3(nblk), dim3(TILE), 0, stream,
                       edge, pos4, radius, out, E);   // direct scalar
    hipLaunchKernelGGL(edge_sh_kernel<1>, dim3(nblk), dim3(TILE), 0, stream,
                       edge, pos4, radius, out, E);   // LDS + regular
    hipLaunchKernelGGL(edge_sh_kernel<0>, dim3(nblk), dim3(TILE), 0, stream,
                       edge, pos4, radius, out, E);   // LDS + nt (control, last)
}

// Round 12
// 657.467 us; speedup vs baseline: 5.3391x; 5.3391x over previous
//
#include <hip/hip_runtime.h>
#include <hip/hip_bf16.h>

// EdgeSHLayer: per-edge radial soft-one-hot (smooth_finite, 10 basis) + SH lmax=2.
// Outputs concatenated: [E*10] embed, then [E*9] sh, both f32.
//
// R12 (= R11 resubmitted; R11 hit GPUAcquisitionTimeout): no-LDS, no-barrier,
// 4-edges-per-thread structure.
//  - R10 probe showed the LDS store skeleton is already near the write roofline
//    (~80 us/iter) and the serial gather+compute phase adds the other ~70 us.
//  - 4 consecutive edges/thread: 2x int4 coalesced index loads, 8 independent
//    pos4 gathers (4x MLP), contiguous per-thread output -> 19 aligned
//    dwordx4 stores (same request count as the LDS drain, zero barriers).
// Identity: sus(1+d)*sus(1-d) = exp(-2/(1-d^2)); scale = 1.14136*e^2*sqrt(10).

#define TILE 256
#define EPT 4   // edges per thread (E=6.4M is divisible; tail path for safety)

typedef float nfloat4 __attribute__((ext_vector_type(4)));

__global__ __launch_bounds__(256) void pack_pos_kernel(
    const float* __restrict__ pos, float4* __restrict__ pos4, int N)
{
    int i = blockIdx.x * 256 + threadIdx.x;
    if (i < N) {
        pos4[i] = make_float4(pos[3 * i + 0], pos[3 * i + 1], pos[3 * i + 2], 0.0f);
    }
}

__device__ __forceinline__ void edge_math(float vx, float vy, float vz,
                                          float inv_step, float* em10, float* sh9)
{
    float len = sqrtf(vx * vx + vy * vy + vz * vz);
    float ls  = len * inv_step;
    #pragma unroll
    for (int j = 0; j < 10; ++j) {
        float d = ls - (float)(j + 1);
        float t = __builtin_fmaf(-d, d, 1.0f);           // 1 - d^2
        em10[j] = (t > 0.0f)
                ? 26.669299714f * __expf(__fdividef(-2.0f, t))
                : 0.0f;
    }
    float inv = 1.0f / fmaxf(len, 1e-12f);
    float x = vx * inv, y = vy * inv, z = vz * inv;
    const float S3 = 1.7320508075688772f;
    sh9[0] = 1.0f;
    sh9[1] = x;  sh9[2] = y;  sh9[3] = z;
    sh9[4] = S3 * x * z;
    sh9[5] = S3 * x * y;
    sh9[6] = y * y - 0.5f * (x * x + z * z);
    sh9[7] = S3 * y * z;
    sh9[8] = 0.5f * S3 * (z * z - x * x);
}

__global__ __launch_bounds__(TILE) void edge_sh_kernel(
    const int*    __restrict__ edge,   // [2, E] int32
    const float4* __restrict__ pos4,   // [N] packed
    const float*  __restrict__ radius, // [1]
    float*        __restrict__ out,    // [E*10 + E*9]
    int E)
{
    const long long t  = (long long)blockIdx.x * TILE + threadIdx.x;
    const long long e0 = t * EPT;
    if (e0 >= (long long)E) return;

    const float inv_step = 11.0f / radius[0];   // (NUM_BASIS+1)/end

    if (e0 + EPT <= (long long)E) {
        // ---- fast path: 4 edges, all vector ----
        int4 s4 = *(const int4*)(edge + e0);                    // coalesced 16B
        int4 d4 = *(const int4*)(edge + (long long)E + e0);     // coalesced 16B
        const int si[4] = {s4.x, s4.y, s4.z, s4.w};
        const int di[4] = {d4.x, d4.y, d4.z, d4.w};

        float vx[4], vy[4], vz[4];
        #pragma unroll
        for (int k = 0; k < 4; ++k) {       // 8 independent gathers in flight
            float4 a = pos4[si[k]];
            float4 b = pos4[di[k]];
            vx[k] = b.x - a.x; vy[k] = b.y - a.y; vz[k] = b.z - a.z;
        }

        float em[40], sh[36];               // all indices compile-time -> regs
        #pragma unroll
        for (int k = 0; k < 4; ++k) {
            edge_math(vx[k], vy[k], vz[k], inv_step, &em[k * 10], &sh[k * 9]);
        }

        // ---- contiguous per-thread stores: 10 + 9 aligned dwordx4 ----
        nfloat4* ge = (nfloat4*)(out + e0 * 10);               // 160B/thread, 16B-aligned
        #pragma unroll
        for (int i = 0; i < 10; ++i) {
            nfloat4 v = {em[4 * i], em[4 * i + 1], em[4 * i + 2], em[4 * i + 3]};
            ge[i] = v;
        }
        nfloat4* gs = (nfloat4*)(out + (long long)E * 10 + e0 * 9);  // 144B/thread
        #pragma unroll
        for (int i = 0; i < 9; ++i) {
            nfloat4 v = {sh[4 * i], sh[4 * i + 1], sh[4 * i + 2], sh[4 * i + 3]};
            gs[i] = v;
        }
    } else {
        // ---- tail: scalar per edge ----
        for (long long e = e0; e < (long long)E; ++e) {
            int s = edge[e];
            int d = edge[(long long)E + e];
            float4 a = pos4[s];
            float4 b = pos4[d];
            float em10[10], sh9[9];
            edge_math(b.x - a.x, b.y - a.y, b.z - a.z, inv_step, em10, sh9);
            float* pe = out + e * 10;
            #pragma unroll
            for (int j = 0; j < 10; ++j) pe[j] = em10[j];
            float* ps = out + (long long)E * 10 + e * 9;
            #pragma unroll
            for (int k = 0; k < 9; ++k) ps[k] = sh9[k];
        }
    }
}

extern "C" void kernel_launch(void* const* d_in, const int* in_sizes, int n_in,
                              void* d_out, int out_size, void* d_ws, size_t ws_size,
                              hipStream_t stream) {
    // inputs: 0=feature (UNUSED), 1=pos [N,3] f32, 2=max_neighbor_radius [1] f32,
    //         3=edge [2,E] int32
    const float* pos    = (const float*)d_in[1];
    const float* radius = (const float*)d_in[2];
    const int*   edge   = (const int*)d_in[3];
    float*       out    = (float*)d_out;

    const int N = in_sizes[1] / 3;
    const int E = in_sizes[3] / 2;

    float4* pos4 = (float4*)d_ws;   // N*16 B = 1.6 MB

    hipLaunchKernelGGL(pack_pos_kernel, dim3((N + 255) / 256), dim3(256), 0, stream,
                       pos, pos4, N);

    const long long threads = ((long long)E + EPT - 1) / EPT;
    const int nblk = (int)((threads + TILE - 1) / TILE);
    hipLaunchKernelGGL(edge_sh_kernel, dim3(nblk), dim3(TILE), 0, stream,
                       edge, pos4, radius, out, E);
}